// Round 4
// baseline (1666.743 us; speedup 1.0000x reference)
//
#include <hip/hip_runtime.h>
#include <math.h>

#define KTOT   1024
#define DIM    64
#define NROWS  (64 * 4096)
#define BLOCK  256

// ws layout: [0,1024) float loss partials (one per block); [1024,2048) float inv_esq

__global__ __launch_bounds__(BLOCK) void vq_prep(const float* __restrict__ emb,
                                                 float* __restrict__ inv_esq) {
    int k = blockIdx.x * BLOCK + threadIdx.x;
    if (k < KTOT) {
        const float4* e4 = (const float4*)(emb + (size_t)k * DIM);
        float s = 0.f;
#pragma unroll
        for (int i = 0; i < DIM / 4; ++i) {
            float4 v = e4[i];
            s += v.x * v.x;
            s += v.y * v.y;
            s += v.z * v.z;
            s += v.w * v.w;
        }
        inv_esq[k] = 1.0f / s;
    }
}

__global__ __launch_bounds__(BLOCK) void vq_main(const float* __restrict__ z_e,
                                                 const float* __restrict__ emb,
                                                 const float* __restrict__ inv_esq,
                                                 float* __restrict__ out_zq,
                                                 float* __restrict__ out_idx,
                                                 float* __restrict__ partials) {
    __shared__ float wred[BLOCK / 64];

    const int tid = threadIdx.x;
    const size_t row = (size_t)blockIdx.x * BLOCK + tid;

    // z row -> 64 VGPRs (fully unrolled, compile-time indexed)
    float z[DIM];
    {
        const float4* zp = (const float4*)(z_e + row * DIM);
#pragma unroll
        for (int i = 0; i < DIM / 4; ++i) *(float4*)&z[4 * i] = zp[i];
    }

    float best = -INFINITY;
    int bestk = 0;

    // Codebook addresses are wave-uniform: either the compiler scalarizes to
    // s_load (SMEM pipe, zero VALU slots), or the TA coalescer collapses 64
    // same-address lanes to one 16B broadcast request (~4.6 TB/s chip-wide
    // worst case, under the 34.5 TB/s L2 ceiling). Either way VALU-bound.
    // Two interleaved accumulator chains: FMA dep-latency ~4 cyc / wave64
    // issue 2 cyc -> 2 chains saturate even at 1 wave/SIMD.
#pragma unroll 2
    for (int k = 0; k < KTOT; ++k) {
        const float4* e4 = (const float4*)(emb + (size_t)k * DIM);
        float a0 = 0.f, a1 = 0.f;
#pragma unroll
        for (int i = 0; i < 16; i += 2) {
            float4 v0 = e4[i];
            float4 v1 = e4[i + 1];
            a0 = fmaf(z[4 * i + 0], v0.x, a0);
            a1 = fmaf(z[4 * i + 4], v1.x, a1);
            a0 = fmaf(z[4 * i + 1], v0.y, a0);
            a1 = fmaf(z[4 * i + 5], v1.y, a1);
            a0 = fmaf(z[4 * i + 2], v0.z, a0);
            a1 = fmaf(z[4 * i + 6], v1.z, a1);
            a0 = fmaf(z[4 * i + 3], v0.w, a0);
            a1 = fmaf(z[4 * i + 7], v1.w, a1);
        }
        float dot = a0 + a1;
        // dist = (z_sq/e_sq[k]/(-2)) * dot ; z_sq>0 => argmin dist == argmax dot/e_sq
        float q = dot * inv_esq[k];          // uniform scalar load
        bool b = q > best;                   // strict >: FIRST max == argmin-first tie-break
        bestk = b ? k : bestk;               // v_cmp + v_cndmask
        best = fmaxf(q, best);               // v_max
    }

    // Epilogue: gather z_q, straight-through output, loss partial.
    const float4* eb = (const float4*)(emb + (size_t)bestk * DIM);
    float4* oz = (float4*)(out_zq + row * DIM);
    float lsum = 0.f;
#pragma unroll
    for (int i = 0; i < 16; ++i) {
        float4 e = eb[i];
        float4 zz = *(const float4*)&z[4 * i];
        float dx = e.x - zz.x, dy = e.y - zz.y, dz = e.z - zz.z, dw = e.w - zz.w;
        float4 o;
        o.x = zz.x + dx;  // z_e + (z_q - z_e): matches reference rounding
        o.y = zz.y + dy;
        o.z = zz.z + dz;
        o.w = zz.w + dw;
        oz[i] = o;
        lsum = fmaf(dx, dx, lsum);
        lsum = fmaf(dy, dy, lsum);
        lsum = fmaf(dz, dz, lsum);
        lsum = fmaf(dw, dw, lsum);
    }
    out_idx[row] = (float)bestk;

    // Deterministic block reduction of loss partial (no atomics).
#pragma unroll
    for (int off = 32; off > 0; off >>= 1) lsum += __shfl_down(lsum, off);
    if ((tid & 63) == 0) wred[tid >> 6] = lsum;
    __syncthreads();
    if (tid == 0) partials[blockIdx.x] = (wred[0] + wred[1]) + (wred[2] + wred[3]);
}

__global__ __launch_bounds__(BLOCK) void vq_finalize(const float* __restrict__ partials,
                                                     float* __restrict__ out_loss) {
    __shared__ double wredd[BLOCK / 64];
    int tid = threadIdx.x;
    double s = 0.0;
    for (int i = tid; i < NROWS / BLOCK; i += BLOCK) s += (double)partials[i];
#pragma unroll
    for (int off = 32; off > 0; off >>= 1) s += __shfl_down(s, off);
    if ((tid & 63) == 0) wredd[tid >> 6] = s;
    __syncthreads();
    if (tid == 0) {
        double tot = (wredd[0] + wredd[1]) + (wredd[2] + wredd[3]);
        float m = (float)(tot / 16777216.0);   // mean over 64*4096*64 elements
        out_loss[0] = m + 0.25f * m;           // m + beta*m, matching reference order
    }
}

extern "C" void kernel_launch(void* const* d_in, const int* in_sizes, int n_in,
                              void* d_out, int out_size, void* d_ws, size_t ws_size,
                              hipStream_t stream) {
    const float* z_e = (const float*)d_in[0];
    const float* emb = (const float*)d_in[1];

    float* out = (float*)d_out;
    float* out_zq = out;                              // 16,777,216 floats
    float* out_idx = out + (size_t)NROWS * DIM;       // 262,144 floats (indices as float)
    float* out_loss = out_idx + NROWS;                // 1 float

    float* partials = (float*)d_ws;                   // 1024 floats (fully rewritten each launch)
    float* inv_esq = partials + (NROWS / BLOCK);      // 1024 floats (fully rewritten each launch)

    vq_prep<<<(KTOT + BLOCK - 1) / BLOCK, BLOCK, 0, stream>>>(emb, inv_esq);
    vq_main<<<NROWS / BLOCK, BLOCK, 0, stream>>>(z_e, emb, inv_esq, out_zq, out_idx, partials);
    vq_finalize<<<1, BLOCK, 0, stream>>>(partials, out_loss);
}